// Round 1
// baseline (1858.050 us; speedup 1.0000x reference)
//
#include <hip/hip_runtime.h>

// LSTM over S=64 steps, one distinct cell per step, bias-free.
// gates[b,j] = sum_k x[b,t,k]*W_ih[t,j,k] + sum_k h[b,k]*W_hh[t,j,k]
// Persistent kernel: 256 WGs x 512 thr, 1 WG/CU. Flag-based step sync.
// bf16 MFMA (16x16x32), fp32 accumulate; W converted in-register (512 MB
// streamed once from HBM = the roofline).

#define NWG  256
#define NTHR 512

constexpr int S  = 64;
constexpr int NB = 64;     // batch
constexpr int IN = 512;
constexpr int H  = 512;
constexpr int BH = NB * H; // 32768 elements

typedef __attribute__((ext_vector_type(8))) short bf16x8;  // 8 bf16 (4 VGPRs)
typedef __attribute__((ext_vector_type(4))) float fx4;

__device__ __forceinline__ short to_bf16(float f) {
  union { float f; unsigned u; } v; v.f = f;
  unsigned r = (v.u + 0x7fffu + ((v.u >> 16) & 1u)) >> 16;  // RNE
  return (short)r;
}
__device__ __forceinline__ bf16x8 cvt8(fx4 a, fx4 b) {
  bf16x8 r;
  r[0] = to_bf16(a[0]); r[1] = to_bf16(a[1]); r[2] = to_bf16(a[2]); r[3] = to_bf16(a[3]);
  r[4] = to_bf16(b[0]); r[5] = to_bf16(b[1]); r[6] = to_bf16(b[2]); r[7] = to_bf16(b[3]);
  return r;
}

__global__ void init_flags(int* flags) {
  flags[blockIdx.x * blockDim.x + threadIdx.x] = 0;
}

__global__ void __launch_bounds__(NTHR, 1) lstm_fused(
    const float* __restrict__ x, const float* __restrict__ Wih,
    const float* __restrict__ Whh, float* __restrict__ out,
    unsigned short* __restrict__ hbuf, int* __restrict__ flags)
{
  // 8 waves x 32 rows x 16 cols of fp32 partials
  __shared__ float red[8 * 32 * 16];

  const int wg   = blockIdx.x;
  const int tid  = threadIdx.x;
  const int wave = tid >> 6;
  const int lane = tid & 63;
  const int cc   = lane & 15;    // MFMA col (gate col) / A-row index
  const int quad = lane >> 4;    // k-subgroup within MFMA
  const int mhalf = wg & 1;      // batch half
  const int ngrp  = wg >> 1;     // 128 groups of 4 h-columns
  const int n0    = ngrp << 2;
  // gate-row in W: gate = cc>>2 (i,f,g,o blocks of 512), within = cc&3
  const int jrow  = ((cc >> 2) << 9) + n0 + (cc & 3);
  const int b0    = (mhalf << 5) + cc;   // A row, m-tile 0
  const int b1    = b0 + 16;             // A row, m-tile 1
  const int kq    = ((wave & 3) << 7) + (quad << 3);  // lane k-base within 512
  const bool is_x = (wave < 4);          // waves 0-3: x-part, 4-7: h-part

  const float* wrow = (is_x ? Wih : Whh) + (size_t)jrow * IN + kq;
  const float* xr0  = x + (size_t)b0 * (S * IN) + kq;  // x[b][t][k], +t*IN per step
  const float* xr1  = x + (size_t)b1 * (S * IN) + kq;
  const unsigned short* hr0 = hbuf + (size_t)b0 * H + kq;
  const unsigned short* hr1 = hbuf + (size_t)b1 * H + kq;

  // cell-update thread mapping (tid < 128)
  const int cm   = tid >> 2;             // 0..31 local batch row
  const int cn   = tid & 3;              // 0..3 local h col
  const int ob   = (mhalf << 5) + cm;
  const int ocol = n0 + cn;
  float c_state  = 0.0f;

  fx4 w[8];  // W tile for current step, prefetched one step ahead
  auto load_w = [&](int tt) {
    const float* wp = wrow + ((size_t)tt << 20);  // t * 2048 * 512
#pragma unroll
    for (int s2 = 0; s2 < 4; ++s2) {
      w[2 * s2]     = *(const fx4*)(wp + (s2 << 5));
      w[2 * s2 + 1] = *(const fx4*)(wp + (s2 << 5) + 4);
    }
  };
  if (is_x) load_w(0);

  for (int t = 0; t < S; ++t) {
    fx4 acc0 = {0.f, 0.f, 0.f, 0.f}, acc1 = {0.f, 0.f, 0.f, 0.f};

    if (is_x) {
      const float* a0 = xr0 + t * IN;
      const float* a1 = xr1 + t * IN;
#pragma unroll
      for (int s2 = 0; s2 < 4; ++s2) {
        bf16x8 wf  = cvt8(w[2 * s2], w[2 * s2 + 1]);
        bf16x8 af0 = cvt8(*(const fx4*)(a0 + (s2 << 5)), *(const fx4*)(a0 + (s2 << 5) + 4));
        bf16x8 af1 = cvt8(*(const fx4*)(a1 + (s2 << 5)), *(const fx4*)(a1 + (s2 << 5) + 4));
        acc0 = __builtin_amdgcn_mfma_f32_16x16x32_bf16(af0, wf, acc0, 0, 0, 0);
        acc1 = __builtin_amdgcn_mfma_f32_16x16x32_bf16(af1, wf, acc1, 0, 0, 0);
      }
      if (t + 1 < S) load_w(t + 1);   // prefetch next W_ih tile across the sync tail
    } else {
      if (t > 0) {
        // wait for all 256 WGs to publish h of step t-1
        const int* fl = flags + ((t - 1) << 8);
        while (true) {
          int f0 = __hip_atomic_load(fl + lane,       __ATOMIC_RELAXED, __HIP_MEMORY_SCOPE_AGENT);
          int f1 = __hip_atomic_load(fl + lane + 64,  __ATOMIC_RELAXED, __HIP_MEMORY_SCOPE_AGENT);
          int f2 = __hip_atomic_load(fl + lane + 128, __ATOMIC_RELAXED, __HIP_MEMORY_SCOPE_AGENT);
          int f3 = __hip_atomic_load(fl + lane + 192, __ATOMIC_RELAXED, __HIP_MEMORY_SCOPE_AGENT);
          if (__ballot((f0 & f1 & f2 & f3) != 0) == ~0ull) break;
          __builtin_amdgcn_s_sleep(4);
        }
        __builtin_amdgcn_fence(__ATOMIC_ACQUIRE, "agent");
        const unsigned short* h0 = hr0 + (size_t)(t & 1) * BH;
        const unsigned short* h1 = hr1 + (size_t)(t & 1) * BH;
#pragma unroll
        for (int s2 = 0; s2 < 4; ++s2) {
          bf16x8 wf  = cvt8(w[2 * s2], w[2 * s2 + 1]);
          bf16x8 af0 = *(const bf16x8*)(h0 + (s2 << 5));
          bf16x8 af1 = *(const bf16x8*)(h1 + (s2 << 5));
          acc0 = __builtin_amdgcn_mfma_f32_16x16x32_bf16(af0, wf, acc0, 0, 0, 0);
          acc1 = __builtin_amdgcn_mfma_f32_16x16x32_bf16(af1, wf, acc1, 0, 0, 0);
        }
      }
      if (t + 1 < S) load_w(t + 1);   // prefetch next W_hh tile
    }

    // stash partials: C row = quad*4 + r (+16 for m-tile 1), col = cc
    const int rbase = (((wave << 5) + (quad << 2)) << 4) + cc;
#pragma unroll
    for (int r = 0; r < 4; ++r) {
      red[rbase + (r << 4)]       = acc0[r];
      red[rbase + 256 + (r << 4)] = acc1[r];
    }
    __syncthreads();

    if (tid < 128) {
      float gv[4];
#pragma unroll
      for (int g = 0; g < 4; ++g) {
        float s = 0.f;
#pragma unroll
        for (int wv = 0; wv < 8; ++wv)
          s += red[(((wv << 5) + cm) << 4) + (g << 2) + cn];
        gv[g] = s;
      }
      float ig = 1.f / (1.f + expf(-gv[0]));
      float fg = 1.f / (1.f + expf(-gv[1]));
      float gg = tanhf(gv[2]);
      float og = 1.f / (1.f + expf(-gv[3]));
      c_state  = fg * c_state + ig * gg;
      float h  = og * tanhf(c_state);
      out[((size_t)ob * S + t) * H + ocol] = h;  // fp32 output, pre-rounding
      hbuf[(size_t)((t + 1) & 1) * BH + (size_t)ob * H + ocol] = (unsigned short)to_bf16(h);
    }
    __syncthreads();  // vmcnt drained for all waves' stores before publish

    if (tid == 0) {
      __builtin_amdgcn_fence(__ATOMIC_RELEASE, "agent");
      __hip_atomic_store(flags + (t << 8) + wg, 1, __ATOMIC_RELAXED, __HIP_MEMORY_SCOPE_AGENT);
    }
  }
}

extern "C" void kernel_launch(void* const* d_in, const int* in_sizes, int n_in,
                              void* d_out, int out_size, void* d_ws, size_t ws_size,
                              hipStream_t stream) {
  const float* x   = (const float*)d_in[0];
  const float* Wih = (const float*)d_in[1];
  const float* Whh = (const float*)d_in[2];
  float* out = (float*)d_out;

  // ws layout: [0,128K) h double-buffer (bf16), [128K,192K) flags[64][256]
  unsigned short* hbuf = (unsigned short*)d_ws;
  int* flags = (int*)((char*)d_ws + (size_t)2 * BH * sizeof(unsigned short));

  hipLaunchKernelGGL(init_flags, dim3(64), dim3(256), 0, stream, flags);  // 16384 ints
  hipLaunchKernelGGL(lstm_fused, dim3(NWG), dim3(NTHR), 0, stream,
                     x, Wih, Whh, out, hbuf, flags);
}

// Round 2
// 903.423 us; speedup vs baseline: 2.0567x; 2.0567x over previous
//
#include <hip/hip_runtime.h>

// LSTM over S=64 steps, one distinct cell per step, bias-free.
// Persistent kernel: 256 WGs x 512 thr, 1 WG/CU. Flag-based step sync.
// bf16 MFMA (16x16x32), fp32 accumulate. Weights (512 MB) streamed once.
//
// R2 change: NO agent-scope fences (they compile to full L2 wbl2/inv per WG
// per step = the R1 23.6us/step stall). All cross-WG state (h, flags) moves
// via device-scope relaxed atomics (sc1 write-through stores / cache-bypass
// loads, single instructions). Ordering: __syncthreads() drains vmcnt(0)
// before the flag publish. Weight prefetch double-buffered in registers and
// issued BEFORE the poll so HBM streams through the sync window.

#define NWG  256
#define NTHR 512

constexpr int S  = 64;
constexpr int NB = 64;     // batch
constexpr int IN = 512;
constexpr int H  = 512;
constexpr int BH = NB * H; // 32768 elements

typedef __attribute__((ext_vector_type(8))) short bf16x8;  // 8 bf16 (4 VGPRs)
typedef __attribute__((ext_vector_type(4))) float fx4;

__device__ __forceinline__ short to_bf16(float f) {
  union { float f; unsigned u; } v; v.f = f;
  unsigned r = (v.u + 0x7fffu + ((v.u >> 16) & 1u)) >> 16;  // RNE
  return (short)r;
}
__device__ __forceinline__ bf16x8 cvt8(fx4 a, fx4 b) {
  bf16x8 r;
  r[0] = to_bf16(a[0]); r[1] = to_bf16(a[1]); r[2] = to_bf16(a[2]); r[3] = to_bf16(a[3]);
  r[4] = to_bf16(b[0]); r[5] = to_bf16(b[1]); r[6] = to_bf16(b[2]); r[7] = to_bf16(b[3]);
  return r;
}
// 4 floats via two 8B device-scope (sc1, cache-bypassing) atomic loads
__device__ __forceinline__ fx4 ld_h4(const float* p) {
  union { unsigned long long u[2]; fx4 f; } v;
  const unsigned long long* q = (const unsigned long long*)p;
  v.u[0] = __hip_atomic_load(q,     __ATOMIC_RELAXED, __HIP_MEMORY_SCOPE_AGENT);
  v.u[1] = __hip_atomic_load(q + 1, __ATOMIC_RELAXED, __HIP_MEMORY_SCOPE_AGENT);
  return v.f;
}
__device__ __forceinline__ float sigm(float x) { return 1.0f / (1.0f + __expf(-x)); }
__device__ __forceinline__ float tanh_f(float x) { return 2.0f / (1.0f + __expf(-2.0f * x)) - 1.0f; }

__global__ void init_flags(int* flags) {
  flags[blockIdx.x * blockDim.x + threadIdx.x] = 0;
}

__global__ void __launch_bounds__(NTHR, 2) lstm_fused(
    const float* __restrict__ x, const float* __restrict__ Wih,
    const float* __restrict__ Whh, float* __restrict__ out,
    float* __restrict__ hbuf, int* __restrict__ flags)
{
  // 8 waves x 32 rows x 16 cols of fp32 partials
  __shared__ float red[8 * 32 * 16];

  const int wg   = blockIdx.x;
  const int tid  = threadIdx.x;
  const int wave = tid >> 6;
  const int lane = tid & 63;
  const int cc   = lane & 15;    // MFMA col (gate col) / A-row index
  const int quad = lane >> 4;    // k-subgroup within MFMA
  const int mhalf = wg & 1;      // batch half
  const int ngrp  = wg >> 1;     // 128 groups of 4 h-columns
  const int n0    = ngrp << 2;
  // gate-row in W: gate = cc>>2 (i,f,g,o blocks of 512), within = cc&3
  const int jrow  = ((cc >> 2) << 9) + n0 + (cc & 3);
  const int b0    = (mhalf << 5) + cc;   // A row, m-tile 0
  const int b1    = b0 + 16;             // A row, m-tile 1
  const int kq    = ((wave & 3) << 7) + (quad << 3);  // lane k-base within 512
  const bool is_x = (wave < 4);          // waves 0-3: x-part, 4-7: h-part

  const float* wrow = (is_x ? Wih : Whh) + (size_t)jrow * IN + kq;
  const float* xr0  = x + (size_t)b0 * (S * IN) + kq;  // x[b][t][k], +t*IN per step
  const float* xr1  = x + (size_t)b1 * (S * IN) + kq;
  const float* hr0  = hbuf + (size_t)b0 * H + kq;      // fp32 h, parity-buffered
  const float* hr1  = hbuf + (size_t)b1 * H + kq;

  // cell-update thread mapping (tid < 128)
  const int cm   = tid >> 2;             // 0..31 local batch row
  const int cn   = tid & 3;              // 0..3 local h col
  const int ob   = (mhalf << 5) + cm;
  const int ocol = n0 + cn;
  float c_state  = 0.0f;

  fx4 wA[8], wB[8];  // double-buffered W tile registers
  auto load_w = [&](fx4 (&w)[8], int tt) {
    const float* wp = wrow + ((size_t)tt << 20);  // t * 2048 * 512
#pragma unroll
    for (int s2 = 0; s2 < 4; ++s2) {
      w[2 * s2]     = *(const fx4*)(wp + (s2 << 5));
      w[2 * s2 + 1] = *(const fx4*)(wp + (s2 << 5) + 4);
    }
  };
  load_w(wA, 0);

  auto step = [&](int t, fx4 (&wc)[8], fx4 (&wn)[8]) {
    // issue next step's weight prefetch FIRST: streams during the sync wait
    if (t + 1 < S) load_w(wn, t + 1);

    fx4 acc0 = {0.f, 0.f, 0.f, 0.f}, acc1 = {0.f, 0.f, 0.f, 0.f};

    if (is_x) {
      const float* a0 = xr0 + t * IN;
      const float* a1 = xr1 + t * IN;
#pragma unroll
      for (int s2 = 0; s2 < 4; ++s2) {
        bf16x8 wf  = cvt8(wc[2 * s2], wc[2 * s2 + 1]);
        bf16x8 af0 = cvt8(*(const fx4*)(a0 + (s2 << 5)), *(const fx4*)(a0 + (s2 << 5) + 4));
        bf16x8 af1 = cvt8(*(const fx4*)(a1 + (s2 << 5)), *(const fx4*)(a1 + (s2 << 5) + 4));
        acc0 = __builtin_amdgcn_mfma_f32_16x16x32_bf16(af0, wf, acc0, 0, 0, 0);
        acc1 = __builtin_amdgcn_mfma_f32_16x16x32_bf16(af1, wf, acc1, 0, 0, 0);
      }
    } else if (t > 0) {
      // wait for all 256 WGs to publish h of step t-1 (sc1 loads, no fences)
      const int* fl = flags + ((t - 1) << 8);
      while (true) {
        int f0 = __hip_atomic_load(fl + lane,       __ATOMIC_RELAXED, __HIP_MEMORY_SCOPE_AGENT);
        int f1 = __hip_atomic_load(fl + lane + 64,  __ATOMIC_RELAXED, __HIP_MEMORY_SCOPE_AGENT);
        int f2 = __hip_atomic_load(fl + lane + 128, __ATOMIC_RELAXED, __HIP_MEMORY_SCOPE_AGENT);
        int f3 = __hip_atomic_load(fl + lane + 192, __ATOMIC_RELAXED, __HIP_MEMORY_SCOPE_AGENT);
        if (__ballot((f0 & f1 & f2 & f3) != 0) == ~0ull) break;
        __builtin_amdgcn_s_sleep(2);
      }
      __asm__ volatile("" ::: "memory");  // compiler barrier: keep h loads below poll
      const float* h0 = hr0 + (size_t)(t & 1) * BH;
      const float* h1 = hr1 + (size_t)(t & 1) * BH;
#pragma unroll
      for (int s2 = 0; s2 < 4; ++s2) {
        bf16x8 wf  = cvt8(wc[2 * s2], wc[2 * s2 + 1]);
        bf16x8 af0 = cvt8(ld_h4(h0 + (s2 << 5)), ld_h4(h0 + (s2 << 5) + 4));
        bf16x8 af1 = cvt8(ld_h4(h1 + (s2 << 5)), ld_h4(h1 + (s2 << 5) + 4));
        acc0 = __builtin_amdgcn_mfma_f32_16x16x32_bf16(af0, wf, acc0, 0, 0, 0);
        acc1 = __builtin_amdgcn_mfma_f32_16x16x32_bf16(af1, wf, acc1, 0, 0, 0);
      }
    }

    // stash partials: C row = quad*4 + r (+16 for m-tile 1), col = cc
    const int rbase = (((wave << 5) + (quad << 2)) << 4) + cc;
#pragma unroll
    for (int r = 0; r < 4; ++r) {
      red[rbase + (r << 4)]       = acc0[r];
      red[rbase + 256 + (r << 4)] = acc1[r];
    }
    __syncthreads();

    if (tid < 128) {
      float gv[4];
#pragma unroll
      for (int g = 0; g < 4; ++g) {
        float s = 0.f;
#pragma unroll
        for (int wv = 0; wv < 8; ++wv)
          s += red[(((wv << 5) + cm) << 4) + (g << 2) + cn];
        gv[g] = s;
      }
      float ig = sigm(gv[0]);
      float fg = sigm(gv[1]);
      float gg = tanh_f(gv[2]);
      float og = sigm(gv[3]);
      c_state  = fg * c_state + ig * gg;
      float h  = og * tanh_f(c_state);
      out[((size_t)ob * S + t) * H + ocol] = h;  // fp32 output (plain, cached)
      // h feedback: sc1 write-through store -> visible at IFC, no L2 residue
      __hip_atomic_store(hbuf + (size_t)(((t + 1) & 1)) * BH + (size_t)ob * H + ocol,
                         h, __ATOMIC_RELAXED, __HIP_MEMORY_SCOPE_AGENT);
    }
    __syncthreads();  // s_waitcnt vmcnt(0) in every wave: h stores at IFC

    if (tid == 0) {
      __hip_atomic_store(flags + (t << 8) + wg, 1, __ATOMIC_RELAXED, __HIP_MEMORY_SCOPE_AGENT);
    }
  };

#pragma unroll 1
  for (int t = 0; t < S; t += 2) {
    step(t,     wA, wB);
    step(t + 1, wB, wA);
  }
}

extern "C" void kernel_launch(void* const* d_in, const int* in_sizes, int n_in,
                              void* d_out, int out_size, void* d_ws, size_t ws_size,
                              hipStream_t stream) {
  const float* x   = (const float*)d_in[0];
  const float* Wih = (const float*)d_in[1];
  const float* Whh = (const float*)d_in[2];
  float* out = (float*)d_out;

  // ws layout: [0,256K) h double-buffer (fp32 2*64*512), [256K,320K) flags[64][256]
  float* hbuf = (float*)d_ws;
  int* flags  = (int*)((char*)d_ws + (size_t)2 * BH * sizeof(float));

  hipLaunchKernelGGL(init_flags, dim3(64), dim3(256), 0, stream, flags);  // 16384 ints
  hipLaunchKernelGGL(lstm_fused, dim3(NWG), dim3(NTHR), 0, stream,
                     x, Wih, Whh, out, hbuf, flags);
}